// Round 5
// baseline (75.453 us; speedup 1.0000x reference)
//
#include <hip/hip_runtime.h>

#define BATCH 32
#define SEQ   2048
#define KD    512
#define QD    1024
#define HD    128

#define NT 16          // K-steps of 32
#define NCHUNK 64      // 32-row chunks per batch

typedef float    f32x4 __attribute__((ext_vector_type(4)));
typedef _Float16 f16x8 __attribute__((ext_vector_type(8)));
typedef unsigned int u32;

__device__ __forceinline__ u32 pack2h(float a, float b) {
    _Float16 ha = (_Float16)a, hb = (_Float16)b;   // v_cvt_f16_f32 (RNE)
    unsigned short ua = __builtin_bit_cast(unsigned short, ha);
    unsigned short ub = __builtin_bit_cast(unsigned short, hb);
    return (u32)ua | ((u32)ub << 16);
}

// two float4 (8 floats) -> f16x8
__device__ __forceinline__ f16x8 cvtA(const float4& r0, const float4& r1) {
    uint4 u = make_uint4(pack2h(r0.x, r0.y), pack2h(r0.z, r0.w),
                         pack2h(r1.x, r1.y), pack2h(r1.z, r1.w));
    return __builtin_bit_cast(f16x8, u);
}

// ---------------------------------------------------------------- prep
// blocks [0,512): q_proj
// blocks [512,528): W2 -> per-fragment f16 images: tile t, frag (hj,lane):
//   w2img[(t*512 + hj*64 + lane)*16B] = f16 of W2[hj*16+(lane&15)][t*32+(lane>>4)*8 .. +8)
__global__ __launch_bounds__(256) void prep_kernel(
        const float* __restrict__ query, const float* __restrict__ W1,
        const float* __restrict__ W2, float* __restrict__ qp,
        char* __restrict__ w2img) {
    int blk = blockIdx.x;
    int tid = threadIdx.x;
    if (blk < 512) {
        int b = blk >> 4, hg = blk & 15;
        int wave = tid >> 6, lane = tid & 63;
        int h = hg * 8 + wave * 2 + (lane >> 5);
        int l32 = lane & 31;
        const float* q = query + (size_t)b * QD;
        const float* w = W1 + (size_t)h * QD;
        float acc = 0.f;
        #pragma unroll
        for (int i = 0; i < 8; ++i) {
            float4 qv = *(const float4*)(q + i * 128 + l32 * 4);
            float4 wv = *(const float4*)(w + i * 128 + l32 * 4);
            acc += qv.x * wv.x + qv.y * wv.y + qv.z * wv.z + qv.w * wv.w;
        }
        #pragma unroll
        for (int off = 16; off >= 1; off >>= 1) acc += __shfl_xor(acc, off);
        if (l32 == 0) qp[b * HD + h] = acc;
    } else {
        int t = blk - 512;
        #pragma unroll
        for (int rep = 0; rep < 2; ++rep) {
            int f  = tid + rep * 256;        // frag 0..511
            int hj = f >> 6;
            int ln = f & 63;
            int r  = hj * 16 + (ln & 15);
            int c  = t * 32 + (ln >> 4) * 8;
            const float* src = W2 + (size_t)r * KD + c;
            float4 v0 = *(const float4*)(src);
            float4 v1 = *(const float4*)(src + 4);
            uint4 u = make_uint4(pack2h(v0.x, v0.y), pack2h(v0.z, v0.w),
                                 pack2h(v1.x, v1.y), pack2h(v1.z, v1.w));
            *(uint4*)(w2img + ((size_t)t * 512 + f) * 16) = u;
        }
    }
}

// ---------------------------------------------------------------- score + ctx partial
// 1 wave per 32 rows. A and B both in registers; NO LDS tiles, NO barriers
// in the K-loop -> no vmcnt(0) drains; compiler manages all waits.
__global__ __launch_bounds__(64, 2) void score_ctx_kernel(
        const float* __restrict__ keys, const char* __restrict__ w2img,
        const float* __restrict__ qp, const float* __restrict__ V,
        float* __restrict__ score_out, float* __restrict__ part_m,
        float* __restrict__ part_l, float* __restrict__ part_c) {
    __shared__ float pb[32];

    const int blk  = blockIdx.x;          // 0..2047
    const int m0   = blk * 32;
    const int b    = blk >> 6;            // 64 chunks per batch
    const int lane = threadIdx.x;
    const int l15  = lane & 15;
    const int l4   = lane >> 4;

    const float* arow0 = keys + (size_t)(m0 + l15) * KD + l4 * 8;
    const float* arow1 = arow0 + 16 * KD;
    const char*  bbase = w2img + lane * 16;

    f32x4 acc[2][8];
    #pragma unroll
    for (int mi = 0; mi < 2; ++mi)
        #pragma unroll
        for (int hj = 0; hj < 8; ++hj)
            acc[mi][hj] = (f32x4)0.f;

    float4 ka[3][4];   // A ring-3 (depth-2 prefetch)
    f16x8  kb[2][8];   // B ring-2 (depth-1 prefetch)

#define KA(slot, t) { \
        ka[slot][0] = *(const float4*)(arow0 + (t) * 32); \
        ka[slot][1] = *(const float4*)(arow0 + (t) * 32 + 4); \
        ka[slot][2] = *(const float4*)(arow1 + (t) * 32); \
        ka[slot][3] = *(const float4*)(arow1 + (t) * 32 + 4); }
#define KB(slot, t) { \
        _Pragma("unroll") \
        for (int hj = 0; hj < 8; ++hj) \
            kb[slot][hj] = *(const f16x8*)(bbase + (t) * 8192 + hj * 1024); }

    KA(0, 0)
    KA(1, 1)
    KB(0, 0)

    #pragma unroll
    for (int t = 0; t < NT; ++t) {
        if (t + 2 < NT) KA((t + 2) % 3, t + 2)
        if (t + 1 < NT) KB((t + 1) & 1, t + 1)

        f16x8 af0 = cvtA(ka[t % 3][0], ka[t % 3][1]);
        f16x8 af1 = cvtA(ka[t % 3][2], ka[t % 3][3]);
        #pragma unroll
        for (int hj = 0; hj < 8; ++hj) {
            acc[0][hj] = __builtin_amdgcn_mfma_f32_16x16x32_f16(af0, kb[t & 1][hj], acc[0][hj], 0, 0, 0);
            acc[1][hj] = __builtin_amdgcn_mfma_f32_16x16x32_f16(af1, kb[t & 1][hj], acc[1][hj], 0, 0, 0);
        }
    }
#undef KA
#undef KB

    // epilogue operands
    float qv[8], vv[8];
    #pragma unroll
    for (int hj = 0; hj < 8; ++hj) {
        qv[hj] = qp[b * HD + hj * 16 + l15];
        vv[hj] = V[hj * 16 + l15];
    }

    // scores; C/D: col(h)=l15, row(m)=mi*16 + l4*4 + j
    float p8[8];
    #pragma unroll
    for (int mi = 0; mi < 2; ++mi) {
        #pragma unroll
        for (int j = 0; j < 4; ++j) {
            float p = 0.f;
            #pragma unroll
            for (int hj = 0; hj < 8; ++hj) {
                float x = qv[hj] + acc[mi][hj][j];
                float e = __expf(2.f * x);
                float th = 1.f - 2.f * __builtin_amdgcn_rcpf(1.f + e);
                p += th * vv[hj];
            }
            #pragma unroll
            for (int off = 1; off < 16; off <<= 1) p += __shfl_xor(p, off);
            p8[mi * 4 + j] = p;
            if (l15 == 0) score_out[m0 + mi * 16 + l4 * 4 + j] = p;
        }
    }

    // wave softmax partials over 32 rows
    float mx = p8[0];
    #pragma unroll
    for (int i = 1; i < 8; ++i) mx = fmaxf(mx, p8[i]);
    mx = fmaxf(mx, __shfl_xor(mx, 16));
    mx = fmaxf(mx, __shfl_xor(mx, 32));
    float e8[8], ls = 0.f;
    #pragma unroll
    for (int i = 0; i < 8; ++i) {
        e8[i] = __expf(p8[i] - mx);
        ls += e8[i];
    }
    ls += __shfl_xor(ls, 16);
    ls += __shfl_xor(ls, 32);
    if (lane == 0) {
        part_m[blk] = mx;
        part_l[blk] = ls;
    }
    if (l15 == 0) {
        #pragma unroll
        for (int mi = 0; mi < 2; ++mi)
            #pragma unroll
            for (int j = 0; j < 4; ++j)
                pb[mi * 16 + l4 * 4 + j] = e8[mi * 4 + j];
    }
    __syncthreads();

    // context partial GEMV over this chunk's 32 rows (keys hot in L2)
    int c0 = lane * 8;
    f32x4 a0 = (f32x4)0.f, a1 = (f32x4)0.f;
    const float* kb2 = keys + (size_t)m0 * KD + c0;
    #pragma unroll 8
    for (int s = 0; s < 32; ++s) {
        float w = pb[s];
        f32x4 k0 = *(const f32x4*)(kb2 + (size_t)s * KD);
        f32x4 k1 = *(const f32x4*)(kb2 + (size_t)s * KD + 4);
        a0 += w * k0;
        a1 += w * k1;
    }
    *(f32x4*)(part_c + (size_t)blk * KD + c0) = a0;
    *(f32x4*)(part_c + (size_t)blk * KD + c0 + 4) = a1;
}

// ---------------------------------------------------------------- finalize
__global__ __launch_bounds__(256) void finalize_kernel(
        const float* __restrict__ part_m, const float* __restrict__ part_l,
        const float* __restrict__ part_c, float* __restrict__ ctx,
        float* __restrict__ wts) {
    __shared__ float eS[NCHUNK];
    int b = blockIdx.x;
    int tid = threadIdx.x;
    float M = -1e30f;
    #pragma unroll 8
    for (int i = 0; i < NCHUNK; ++i) M = fmaxf(M, part_m[b * NCHUNK + i]);
    if (tid < NCHUNK) eS[tid] = __expf(part_m[b * NCHUNK + tid] - M);
    __syncthreads();
    float L = 0.f;
    #pragma unroll 8
    for (int i = 0; i < NCHUNK; ++i) L += eS[i] * part_l[b * NCHUNK + i];
    float invL = 1.f / L;
    #pragma unroll
    for (int r = 0; r < 8; ++r) {
        int s = tid + r * 256;
        float scv = wts[b * SEQ + s];
        wts[b * SEQ + s] = __expf(scv - M) * invL;
    }
    int col = tid * 2;
    float c0 = 0.f, c1 = 0.f;
    #pragma unroll 8
    for (int i = 0; i < NCHUNK; ++i) {
        float w = eS[i];
        float2 pc = *(const float2*)(part_c + (size_t)(b * NCHUNK + i) * KD + col);
        c0 = fmaf(w, pc.x, c0);
        c1 = fmaf(w, pc.y, c1);
    }
    ctx[b * KD + col]     = c0 * invL;
    ctx[b * KD + col + 1] = c1 * invL;
}

// ---------------------------------------------------------------- launch
extern "C" void kernel_launch(void* const* d_in, const int* in_sizes, int n_in,
                              void* d_out, int out_size, void* d_ws, size_t ws_size,
                              hipStream_t stream) {
    const float* query = (const float*)d_in[0];
    const float* keys  = (const float*)d_in[1];
    const float* W1    = (const float*)d_in[2];
    const float* W2    = (const float*)d_in[3];
    const float* V     = (const float*)d_in[4];

    float* ctx = (float*)d_out;
    float* wts = (float*)d_out + BATCH * KD;

    char* wsb     = (char*)d_ws;
    float* qp     = (float*)wsb;                       // 16 KB
    char*  w2img  = wsb + 16 * 1024;                   // 128 KB
    float* part_m = (float*)(wsb + 144 * 1024);        // 8 KB
    float* part_l = (float*)(wsb + 152 * 1024);        // 8 KB
    float* part_c = (float*)(wsb + 160 * 1024);        // 4 MB

    prep_kernel<<<528, 256, 0, stream>>>(query, W1, W2, qp, w2img);
    score_ctx_kernel<<<BATCH * NCHUNK, 64, 0, stream>>>(
        keys, w2img, qp, V, wts, part_m, part_l, part_c);
    finalize_kernel<<<BATCH, 256, 0, stream>>>(part_m, part_l, part_c, ctx, wts);
}

// Round 6
// 58.059 us; speedup vs baseline: 1.2996x; 1.2996x over previous
//
#include <hip/hip_runtime.h>

#define BATCH 32
#define SEQ   2048
#define KD    512
#define QD    1024
#define HD    128

#define NT 16          // K-steps of 32
#define ROWS 64        // rows per block (16 per wave)
#define NCHUNK 32      // 64-row chunks per batch

typedef float    f32x4 __attribute__((ext_vector_type(4)));
typedef _Float16 f16x8 __attribute__((ext_vector_type(8)));
typedef unsigned int u32;

__device__ __forceinline__ u32 pack2h(float a, float b) {
    _Float16 ha = (_Float16)a, hb = (_Float16)b;   // v_cvt_f16_f32 (RNE)
    unsigned short ua = __builtin_bit_cast(unsigned short, ha);
    unsigned short ub = __builtin_bit_cast(unsigned short, hb);
    return (u32)ua | ((u32)ub << 16);
}

// 16 fp32 (f32x4[4]) -> two uint4 of packed f16
__device__ __forceinline__ void cvt16(const f32x4 a[4], uint4& h0, uint4& h1) {
    h0 = make_uint4(pack2h(a[0][0], a[0][1]), pack2h(a[0][2], a[0][3]),
                    pack2h(a[1][0], a[1][1]), pack2h(a[1][2], a[1][3]));
    h1 = make_uint4(pack2h(a[2][0], a[2][1]), pack2h(a[2][2], a[2][3]),
                    pack2h(a[3][0], a[3][1]), pack2h(a[3][2], a[3][3]));
}

// two float4 (8 floats, one A-frag row) -> f16x8
__device__ __forceinline__ f16x8 cvtA(const float4& r0, const float4& r1) {
    uint4 u = make_uint4(pack2h(r0.x, r0.y), pack2h(r0.z, r0.w),
                         pack2h(r1.x, r1.y), pack2h(r1.z, r1.w));
    return __builtin_bit_cast(f16x8, u);
}

__device__ __forceinline__ void gload_lds16(const void* g, void* l) {
    __builtin_amdgcn_global_load_lds(
        (const __attribute__((address_space(1))) unsigned int*)g,
        (__attribute__((address_space(3))) unsigned int*)l, 16, 0, 0);
}

// ---------------------------------------------------------------- prep
// blocks [0,512): q_proj ; blocks [512,528): W2 -> f16 swizzled tile images
// (8 KB per K-step; linear gload_lds copy lands in XOR-swizzled LDS form)
__global__ __launch_bounds__(256) void prep_kernel(
        const float* __restrict__ query, const float* __restrict__ W1,
        const float* __restrict__ W2, float* __restrict__ qp,
        char* __restrict__ w2img) {
    int blk = blockIdx.x;
    int tid = threadIdx.x;
    if (blk < 512) {
        int b = blk >> 4, hg = blk & 15;
        int wave = tid >> 6, lane = tid & 63;
        int h = hg * 8 + wave * 2 + (lane >> 5);
        int l32 = lane & 31;
        const float* q = query + (size_t)b * QD;
        const float* w = W1 + (size_t)h * QD;
        float acc = 0.f;
        #pragma unroll
        for (int i = 0; i < 8; ++i) {
            float4 qv = *(const float4*)(q + i * 128 + l32 * 4);
            float4 wv = *(const float4*)(w + i * 128 + l32 * 4);
            acc += qv.x * wv.x + qv.y * wv.y + qv.z * wv.z + qv.w * wv.w;
        }
        #pragma unroll
        for (int off = 16; off >= 1; off >>= 1) acc += __shfl_xor(acc, off);
        if (l32 == 0) qp[b * HD + h] = acc;
    } else {
        int c = blk - 512;              // K chunk
        int row = tid >> 1;             // h row 0..127
        int scol = (tid & 1) * 16;      // element col within 32
        const float* src = W2 + (size_t)row * KD + c * 32 + scol;
        f32x4 a[4];
        #pragma unroll
        for (int i = 0; i < 4; ++i) a[i] = *(const f32x4*)(src + i * 4);
        uint4 h0, h1;
        cvt16(a, h0, h1);
        int sw = (row & 7) << 4;
        int b0 = c * 8192 + ((row * 64 + scol * 2) ^ sw);
        int b1 = c * 8192 + ((row * 64 + scol * 2 + 16) ^ sw);
        *(uint4*)(w2img + b0) = h0;
        *(uint4*)(w2img + b1) = h1;
    }
}

// ---------------------------------------------------------------- score + ctx partial
// 4 waves x 16 rows = 64 rows/block, 1024 blocks -> 16 waves/CU.
// A: global->reg->cvt->MFMA (ring-2). B: LDS double-buffer via gload_lds,
// plain __syncthreads (R2-proven race-free pattern); barrier drain covered
// by 3 other co-resident blocks per CU.
__global__ __launch_bounds__(256, 4) void score_ctx_kernel(
        const float* __restrict__ keys, const char* __restrict__ w2img,
        const float* __restrict__ qp, const float* __restrict__ V,
        float* __restrict__ score_out, float* __restrict__ part_m,
        float* __restrict__ part_l, float* __restrict__ part_c) {
    __shared__ __align__(16) char Bl[2][8192];
    __shared__ float sc[ROWS];
    __shared__ float pb[ROWS];

    const int blk  = blockIdx.x;          // 0..1023
    const int m0   = blk * ROWS;
    const int b    = blk >> 5;            // 32 chunks per batch
    const int tid  = threadIdx.x;
    const int wave = tid >> 6;
    const int lane = tid & 63;
    const int l15  = lane & 15;
    const int l4   = lane >> 4;

    // A source: row = m0 + wave*16 + l15, col base l4*8
    const float* arow = keys + (size_t)(m0 + wave * 16 + l15) * KD + l4 * 8;
    // B frag byte offset within an 8 KB swizzled tile
    const int boff0 = (l15 * 64 + l4 * 16) ^ ((l15 & 7) << 4);

    f32x4 acc[8];
    #pragma unroll
    for (int hj = 0; hj < 8; ++hj) acc[hj] = (f32x4)0.f;

    float4 ka[2][2];   // A ring-2

#define KA(slot, t) { \
        ka[slot][0] = *(const float4*)(arow + (t) * 32); \
        ka[slot][1] = *(const float4*)(arow + (t) * 32 + 4); }
#define BSTAGE(slot, t) { \
        const char* g_ = w2img + (t) * 8192 + wave * 2048 + lane * 16; \
        gload_lds16(g_,        &Bl[slot][wave * 2048]); \
        gload_lds16(g_ + 1024, &Bl[slot][wave * 2048 + 1024]); }

    BSTAGE(0, 0)
    KA(0, 0)
    __syncthreads();

    #pragma unroll
    for (int t = 0; t < NT; ++t) {
        const int cb = t & 1, nb = cb ^ 1;
        if (t + 1 < NT) {
            BSTAGE(nb, t + 1)
            KA(nb, t + 1)
        }
        f16x8 af = cvtA(ka[cb][0], ka[cb][1]);
        #pragma unroll
        for (int hj = 0; hj < 8; ++hj) {
            f16x8 bh = *(const f16x8*)(&Bl[cb][boff0 + hj * 1024]);
            acc[hj] = __builtin_amdgcn_mfma_f32_16x16x32_f16(af, bh, acc[hj], 0, 0, 0);
        }
        __syncthreads();
    }
#undef KA
#undef BSTAGE

    // epilogue operands
    float qv[8], vv[8];
    #pragma unroll
    for (int hj = 0; hj < 8; ++hj) {
        qv[hj] = qp[b * HD + hj * 16 + l15];
        vv[hj] = V[hj * 16 + l15];
    }

    // scores; C/D: col(h)=l15, row(m)=l4*4+j
    #pragma unroll
    for (int j = 0; j < 4; ++j) {
        float p = 0.f;
        #pragma unroll
        for (int hj = 0; hj < 8; ++hj) {
            float x = qv[hj] + acc[hj][j];
            float e = __expf(2.f * x);
            float th = 1.f - 2.f * __builtin_amdgcn_rcpf(1.f + e);
            p += th * vv[hj];
        }
        #pragma unroll
        for (int off = 1; off < 16; off <<= 1) p += __shfl_xor(p, off);
        if (l15 == 0) {
            int r = wave * 16 + l4 * 4 + j;
            score_out[m0 + r] = p;
            sc[r] = p;
        }
    }
    __syncthreads();

    // block softmax partials over 64 rows (each wave computes identically)
    float s_val = sc[lane];               // lanes 0..63 <-> rows 0..63
    float mx = s_val;
    #pragma unroll
    for (int off = 32; off >= 1; off >>= 1) mx = fmaxf(mx, __shfl_xor(mx, off));
    float p = __expf(s_val - mx);
    float ls = p;
    #pragma unroll
    for (int off = 32; off >= 1; off >>= 1) ls += __shfl_xor(ls, off);
    if (wave == 0) pb[lane] = p;
    if (tid == 0) {
        part_m[blk] = mx;
        part_l[blk] = ls;
    }
    __syncthreads();

    // context partial GEMV: c[col] = sum_s pb[s] * keys[m0+s, col]  (L2-hot)
    int col = tid * 2;
    float c0 = 0.f, c1 = 0.f;
    const float* kb2 = keys + (size_t)m0 * KD + col;
    #pragma unroll 8
    for (int s = 0; s < ROWS; ++s) {
        float w = pb[s];
        float2 kv = *(const float2*)(kb2 + (size_t)s * KD);
        c0 = fmaf(w, kv.x, c0);
        c1 = fmaf(w, kv.y, c1);
    }
    *(float2*)(part_c + (size_t)blk * KD + col) = make_float2(c0, c1);
}

// ---------------------------------------------------------------- finalize
__global__ __launch_bounds__(256) void finalize_kernel(
        const float* __restrict__ part_m, const float* __restrict__ part_l,
        const float* __restrict__ part_c, float* __restrict__ ctx,
        float* __restrict__ wts) {
    __shared__ float eS[NCHUNK];
    int b = blockIdx.x;
    int tid = threadIdx.x;
    float M = -1e30f;
    #pragma unroll 8
    for (int i = 0; i < NCHUNK; ++i) M = fmaxf(M, part_m[b * NCHUNK + i]);
    if (tid < NCHUNK) eS[tid] = __expf(part_m[b * NCHUNK + tid] - M);
    __syncthreads();
    float L = 0.f;
    #pragma unroll 8
    for (int i = 0; i < NCHUNK; ++i) L += eS[i] * part_l[b * NCHUNK + i];
    float invL = 1.f / L;
    #pragma unroll
    for (int r = 0; r < 8; ++r) {
        int s = tid + r * 256;
        float scv = wts[b * SEQ + s];
        wts[b * SEQ + s] = __expf(scv - M) * invL;
    }
    int col = tid * 2;
    float c0 = 0.f, c1 = 0.f;
    #pragma unroll 8
    for (int i = 0; i < NCHUNK; ++i) {
        float w = eS[i];
        float2 pc = *(const float2*)(part_c + (size_t)(b * NCHUNK + i) * KD + col);
        c0 = fmaf(w, pc.x, c0);
        c1 = fmaf(w, pc.y, c1);
    }
    ctx[b * KD + col]     = c0 * invL;
    ctx[b * KD + col + 1] = c1 * invL;
}

// ---------------------------------------------------------------- launch
extern "C" void kernel_launch(void* const* d_in, const int* in_sizes, int n_in,
                              void* d_out, int out_size, void* d_ws, size_t ws_size,
                              hipStream_t stream) {
    const float* query = (const float*)d_in[0];
    const float* keys  = (const float*)d_in[1];
    const float* W1    = (const float*)d_in[2];
    const float* W2    = (const float*)d_in[3];
    const float* V     = (const float*)d_in[4];

    float* ctx = (float*)d_out;
    float* wts = (float*)d_out + BATCH * KD;

    char* wsb     = (char*)d_ws;
    float* qp     = (float*)wsb;                       // 16 KB
    char*  w2img  = wsb + 16 * 1024;                   // 128 KB
    float* part_m = (float*)(wsb + 144 * 1024);        // 4 KB
    float* part_l = (float*)(wsb + 148 * 1024);        // 4 KB
    float* part_c = (float*)(wsb + 152 * 1024);        // 2 MB

    prep_kernel<<<528, 256, 0, stream>>>(query, W1, W2, qp, w2img);
    score_ctx_kernel<<<BATCH * NCHUNK, 256, 0, stream>>>(
        keys, w2img, qp, V, wts, part_m, part_l, part_c);
    finalize_kernel<<<BATCH, 256, 0, stream>>>(part_m, part_l, part_c, ctx, wts);
}

// Round 7
// 57.979 us; speedup vs baseline: 1.3014x; 1.0014x over previous
//
#include <hip/hip_runtime.h>

#define BATCH 32
#define SEQ   2048
#define KD    512
#define QD    1024
#define HD    128

#define NT 8           // K-steps of 64
#define ROWS 64        // rows per block (16 per wave)
#define NCHUNK 32      // 64-row chunks per batch

typedef float    f32x4 __attribute__((ext_vector_type(4)));
typedef _Float16 f16x8 __attribute__((ext_vector_type(8)));
typedef unsigned int u32;

__device__ __forceinline__ u32 pack2h(float a, float b) {
    _Float16 ha = (_Float16)a, hb = (_Float16)b;   // v_cvt_f16_f32 (RNE)
    unsigned short ua = __builtin_bit_cast(unsigned short, ha);
    unsigned short ub = __builtin_bit_cast(unsigned short, hb);
    return (u32)ua | ((u32)ub << 16);
}

// 16 fp32 (f32x4[4]) -> two uint4 of packed f16
__device__ __forceinline__ void cvt16(const f32x4 a[4], uint4& h0, uint4& h1) {
    h0 = make_uint4(pack2h(a[0][0], a[0][1]), pack2h(a[0][2], a[0][3]),
                    pack2h(a[1][0], a[1][1]), pack2h(a[1][2], a[1][3]));
    h1 = make_uint4(pack2h(a[2][0], a[2][1]), pack2h(a[2][2], a[2][3]),
                    pack2h(a[3][0], a[3][1]), pack2h(a[3][2], a[3][3]));
}

// two float4 (8 floats, one A-frag k-sub) -> f16x8
__device__ __forceinline__ f16x8 cvtA(const float4& r0, const float4& r1) {
    uint4 u = make_uint4(pack2h(r0.x, r0.y), pack2h(r0.z, r0.w),
                         pack2h(r1.x, r1.y), pack2h(r1.z, r1.w));
    return __builtin_bit_cast(f16x8, u);
}

__device__ __forceinline__ void gload_lds16(const void* g, void* l) {
    __builtin_amdgcn_global_load_lds(
        (const __attribute__((address_space(1))) unsigned int*)g,
        (__attribute__((address_space(3))) unsigned int*)l, 16, 0, 0);
}

// ---------------------------------------------------------------- prep
// blocks [0,512): q_proj ; blocks [512,528): W2 -> f16 swizzled 8 KB images
// (one per 32-k chunk; linear gload_lds copy lands in XOR-swizzled LDS form)
__global__ __launch_bounds__(256) void prep_kernel(
        const float* __restrict__ query, const float* __restrict__ W1,
        const float* __restrict__ W2, float* __restrict__ qp,
        char* __restrict__ w2img) {
    int blk = blockIdx.x;
    int tid = threadIdx.x;
    if (blk < 512) {
        int b = blk >> 4, hg = blk & 15;
        int wave = tid >> 6, lane = tid & 63;
        int h = hg * 8 + wave * 2 + (lane >> 5);
        int l32 = lane & 31;
        const float* q = query + (size_t)b * QD;
        const float* w = W1 + (size_t)h * QD;
        float acc = 0.f;
        #pragma unroll
        for (int i = 0; i < 8; ++i) {
            float4 qv = *(const float4*)(q + i * 128 + l32 * 4);
            float4 wv = *(const float4*)(w + i * 128 + l32 * 4);
            acc += qv.x * wv.x + qv.y * wv.y + qv.z * wv.z + qv.w * wv.w;
        }
        #pragma unroll
        for (int off = 16; off >= 1; off >>= 1) acc += __shfl_xor(acc, off);
        if (l32 == 0) qp[b * HD + h] = acc;
    } else {
        int c = blk - 512;              // 32-k chunk 0..15
        int row = tid >> 1;             // h row 0..127
        int scol = (tid & 1) * 16;      // element col within 32
        const float* src = W2 + (size_t)row * KD + c * 32 + scol;
        f32x4 a[4];
        #pragma unroll
        for (int i = 0; i < 4; ++i) a[i] = *(const f32x4*)(src + i * 4);
        uint4 h0, h1;
        cvt16(a, h0, h1);
        int sw = (row & 7) << 4;
        int b0 = c * 8192 + ((row * 64 + scol * 2) ^ sw);
        int b1 = c * 8192 + ((row * 64 + scol * 2 + 16) ^ sw);
        *(uint4*)(w2img + b0) = h0;
        *(uint4*)(w2img + b1) = h1;
    }
}

// ---------------------------------------------------------------- score + ctx partial
// 4 waves x 16 rows = 64 rows/block, 1024 blocks -> 4 blocks/CU, 16 waves/CU.
// BK=64: 16 MFMAs per wave between barriers, 8 barrier-drains total.
// A: global->reg->cvt->MFMA (ring-2). B: two 8 KB images per step, LDS
// double-buffer via gload_lds, plain __syncthreads (race-free pattern).
__global__ __launch_bounds__(256, 4) void score_ctx_kernel(
        const float* __restrict__ keys, const char* __restrict__ w2img,
        const float* __restrict__ qp, const float* __restrict__ V,
        float* __restrict__ score_out, float* __restrict__ part_m,
        float* __restrict__ part_l, float* __restrict__ part_c) {
    __shared__ __align__(16) char Bl[2][16384];
    __shared__ float sc[ROWS];
    __shared__ float pb[ROWS];

    const int blk  = blockIdx.x;          // 0..1023
    const int m0   = blk * ROWS;
    const int b    = blk >> 5;            // 32 chunks per batch
    const int tid  = threadIdx.x;
    const int wave = tid >> 6;
    const int lane = tid & 63;
    const int l15  = lane & 15;
    const int l4   = lane >> 4;

    // A source: row = m0 + wave*16 + l15, col base l4*8
    const float* arow = keys + (size_t)(m0 + wave * 16 + l15) * KD + l4 * 8;
    // B frag byte offset within an 8 KB swizzled image
    const int boff0 = (l15 * 64 + l4 * 16) ^ ((l15 & 7) << 4);

    f32x4 acc[8];
    #pragma unroll
    for (int hj = 0; hj < 8; ++hj) acc[hj] = (f32x4)0.f;

    float4 ka[2][4];   // A ring-2, 16 floats each (two k-subs)

#define KA(slot, t) { \
        ka[slot][0] = *(const float4*)(arow + (t) * 64); \
        ka[slot][1] = *(const float4*)(arow + (t) * 64 + 4); \
        ka[slot][2] = *(const float4*)(arow + (t) * 64 + 32); \
        ka[slot][3] = *(const float4*)(arow + (t) * 64 + 36); }
#define BSTAGE(slot, t) { \
        const char* g0_ = w2img + (2 * (t)) * 8192 + wave * 2048 + lane * 16; \
        gload_lds16(g0_,        &Bl[slot][wave * 2048]); \
        gload_lds16(g0_ + 1024, &Bl[slot][wave * 2048 + 1024]); \
        const char* g1_ = g0_ + 8192; \
        gload_lds16(g1_,        &Bl[slot][8192 + wave * 2048]); \
        gload_lds16(g1_ + 1024, &Bl[slot][8192 + wave * 2048 + 1024]); }

    BSTAGE(0, 0)
    KA(0, 0)
    __syncthreads();

    #pragma unroll
    for (int t = 0; t < NT; ++t) {
        const int cb = t & 1, nb = cb ^ 1;
        if (t + 1 < NT) {
            BSTAGE(nb, t + 1)
            KA(nb, t + 1)
        }
        #pragma unroll
        for (int ks = 0; ks < 2; ++ks) {
            f16x8 af = cvtA(ka[cb][ks * 2], ka[cb][ks * 2 + 1]);
            #pragma unroll
            for (int hj = 0; hj < 8; ++hj) {
                f16x8 bh = *(const f16x8*)(&Bl[cb][ks * 8192 + boff0 + hj * 1024]);
                acc[hj] = __builtin_amdgcn_mfma_f32_16x16x32_f16(af, bh, acc[hj], 0, 0, 0);
            }
        }
        __syncthreads();
    }
#undef KA
#undef BSTAGE

    // epilogue operands
    float qv[8], vv[8];
    #pragma unroll
    for (int hj = 0; hj < 8; ++hj) {
        qv[hj] = qp[b * HD + hj * 16 + l15];
        vv[hj] = V[hj * 16 + l15];
    }

    // scores; C/D: col(h)=l15, row(m)=l4*4+j
    #pragma unroll
    for (int j = 0; j < 4; ++j) {
        float p = 0.f;
        #pragma unroll
        for (int hj = 0; hj < 8; ++hj) {
            float x = qv[hj] + acc[hj][j];
            float e = __expf(2.f * x);
            float th = 1.f - 2.f * __builtin_amdgcn_rcpf(1.f + e);
            p += th * vv[hj];
        }
        #pragma unroll
        for (int off = 1; off < 16; off <<= 1) p += __shfl_xor(p, off);
        if (l15 == 0) {
            int r = wave * 16 + l4 * 4 + j;
            score_out[m0 + r] = p;
            sc[r] = p;
        }
    }
    __syncthreads();

    // block softmax partials over 64 rows
    float s_val = sc[lane];               // lanes 0..63 <-> rows 0..63
    float mx = s_val;
    #pragma unroll
    for (int off = 32; off >= 1; off >>= 1) mx = fmaxf(mx, __shfl_xor(mx, off));
    float p = __expf(s_val - mx);
    float ls = p;
    #pragma unroll
    for (int off = 32; off >= 1; off >>= 1) ls += __shfl_xor(ls, off);
    if (wave == 0) pb[lane] = p;
    if (tid == 0) {
        part_m[blk] = mx;
        part_l[blk] = ls;
    }
    __syncthreads();

    // context partial GEMV: c[col] = sum_s pb[s] * keys[m0+s, col]  (L2-hot)
    int col = tid * 2;
    float c0 = 0.f, c1 = 0.f;
    const float* kb2 = keys + (size_t)m0 * KD + col;
    #pragma unroll 8
    for (int s = 0; s < ROWS; ++s) {
        float w = pb[s];
        float2 kv = *(const float2*)(kb2 + (size_t)s * KD);
        c0 = fmaf(w, kv.x, c0);
        c1 = fmaf(w, kv.y, c1);
    }
    *(float2*)(part_c + (size_t)blk * KD + col) = make_float2(c0, c1);
}

// ---------------------------------------------------------------- finalize
__global__ __launch_bounds__(256) void finalize_kernel(
        const float* __restrict__ part_m, const float* __restrict__ part_l,
        const float* __restrict__ part_c, float* __restrict__ ctx,
        float* __restrict__ wts) {
    __shared__ float eS[NCHUNK];
    int b = blockIdx.x;
    int tid = threadIdx.x;
    float M = -1e30f;
    #pragma unroll 8
    for (int i = 0; i < NCHUNK; ++i) M = fmaxf(M, part_m[b * NCHUNK + i]);
    if (tid < NCHUNK) eS[tid] = __expf(part_m[b * NCHUNK + tid] - M);
    __syncthreads();
    float L = 0.f;
    #pragma unroll 8
    for (int i = 0; i < NCHUNK; ++i) L += eS[i] * part_l[b * NCHUNK + i];
    float invL = 1.f / L;
    #pragma unroll
    for (int r = 0; r < 8; ++r) {
        int s = tid + r * 256;
        float scv = wts[b * SEQ + s];
        wts[b * SEQ + s] = __expf(scv - M) * invL;
    }
    int col = tid * 2;
    float c0 = 0.f, c1 = 0.f;
    #pragma unroll 8
    for (int i = 0; i < NCHUNK; ++i) {
        float w = eS[i];
        float2 pc = *(const float2*)(part_c + (size_t)(b * NCHUNK + i) * KD + col);
        c0 = fmaf(w, pc.x, c0);
        c1 = fmaf(w, pc.y, c1);
    }
    ctx[b * KD + col]     = c0 * invL;
    ctx[b * KD + col + 1] = c1 * invL;
}

// ---------------------------------------------------------------- launch
extern "C" void kernel_launch(void* const* d_in, const int* in_sizes, int n_in,
                              void* d_out, int out_size, void* d_ws, size_t ws_size,
                              hipStream_t stream) {
    const float* query = (const float*)d_in[0];
    const float* keys  = (const float*)d_in[1];
    const float* W1    = (const float*)d_in[2];
    const float* W2    = (const float*)d_in[3];
    const float* V     = (const float*)d_in[4];

    float* ctx = (float*)d_out;
    float* wts = (float*)d_out + BATCH * KD;

    char* wsb     = (char*)d_ws;
    float* qp     = (float*)wsb;                       // 16 KB
    char*  w2img  = wsb + 16 * 1024;                   // 128 KB
    float* part_m = (float*)(wsb + 144 * 1024);        // 4 KB
    float* part_l = (float*)(wsb + 148 * 1024);        // 4 KB
    float* part_c = (float*)(wsb + 152 * 1024);        // 2 MB

    prep_kernel<<<528, 256, 0, stream>>>(query, W1, W2, qp, w2img);
    score_ctx_kernel<<<BATCH * NCHUNK, 256, 0, stream>>>(
        keys, w2img, qp, V, wts, part_m, part_l, part_c);
    finalize_kernel<<<BATCH, 256, 0, stream>>>(part_m, part_l, part_c, ctx, wts);
}

// Round 8
// 52.487 us; speedup vs baseline: 1.4375x; 1.1046x over previous
//
#include <hip/hip_runtime.h>

#define BATCH 32
#define SEQ   2048
#define KD    512
#define QD    1024
#define HD    128

#define NT 16          // K-steps of 32
#define ROWS 128       // rows per block (32 per wave)
#define NCHUNK 16      // 128-row chunks per batch

typedef float    f32x4 __attribute__((ext_vector_type(4)));
typedef _Float16 f16x8 __attribute__((ext_vector_type(8)));
typedef unsigned int u32;

__device__ __forceinline__ u32 pack2h(float a, float b) {
    _Float16 ha = (_Float16)a, hb = (_Float16)b;   // v_cvt_f16_f32 (RNE)
    unsigned short ua = __builtin_bit_cast(unsigned short, ha);
    unsigned short ub = __builtin_bit_cast(unsigned short, hb);
    return (u32)ua | ((u32)ub << 16);
}

// 16 fp32 (f32x4[4]) -> two uint4 of packed f16
__device__ __forceinline__ void cvt16(const f32x4 a[4], uint4& h0, uint4& h1) {
    h0 = make_uint4(pack2h(a[0][0], a[0][1]), pack2h(a[0][2], a[0][3]),
                    pack2h(a[1][0], a[1][1]), pack2h(a[1][2], a[1][3]));
    h1 = make_uint4(pack2h(a[2][0], a[2][1]), pack2h(a[2][2], a[2][3]),
                    pack2h(a[3][0], a[3][1]), pack2h(a[3][2], a[3][3]));
}

// two f32x4 (8 floats) -> f16x8
__device__ __forceinline__ f16x8 cvtA4(const f32x4& r0, const f32x4& r1) {
    uint4 u = make_uint4(pack2h(r0[0], r0[1]), pack2h(r0[2], r0[3]),
                         pack2h(r1[0], r1[1]), pack2h(r1[2], r1[3]));
    return __builtin_bit_cast(f16x8, u);
}

__device__ __forceinline__ void gload_lds16(const void* g, void* l) {
    __builtin_amdgcn_global_load_lds(
        (const __attribute__((address_space(1))) unsigned int*)g,
        (__attribute__((address_space(3))) unsigned int*)l, 16, 0, 0);
}

// ---------------------------------------------------------------- prep
// blocks [0,512): q_proj ; blocks [512,528): W2 -> f16 swizzled 8 KB images
__global__ __launch_bounds__(256) void prep_kernel(
        const float* __restrict__ query, const float* __restrict__ W1,
        const float* __restrict__ W2, float* __restrict__ qp,
        char* __restrict__ w2img) {
    int blk = blockIdx.x;
    int tid = threadIdx.x;
    if (blk < 512) {
        int b = blk >> 4, hg = blk & 15;
        int wave = tid >> 6, lane = tid & 63;
        int h = hg * 8 + wave * 2 + (lane >> 5);
        int l32 = lane & 31;
        const float* q = query + (size_t)b * QD;
        const float* w = W1 + (size_t)h * QD;
        float acc = 0.f;
        #pragma unroll
        for (int i = 0; i < 8; ++i) {
            float4 qv = *(const float4*)(q + i * 128 + l32 * 4);
            float4 wv = *(const float4*)(w + i * 128 + l32 * 4);
            acc += qv.x * wv.x + qv.y * wv.y + qv.z * wv.z + qv.w * wv.w;
        }
        #pragma unroll
        for (int off = 16; off >= 1; off >>= 1) acc += __shfl_xor(acc, off);
        if (l32 == 0) qp[b * HD + h] = acc;
    } else {
        int c = blk - 512;              // 32-col chunk 0..15
        int row = tid >> 1;             // h row 0..127
        int scol = (tid & 1) * 16;      // element col within 32
        const float* src = W2 + (size_t)row * KD + c * 32 + scol;
        f32x4 a[4];
        #pragma unroll
        for (int i = 0; i < 4; ++i) a[i] = *(const f32x4*)(src + i * 4);
        uint4 h0, h1;
        cvt16(a, h0, h1);
        int sw = (row & 7) << 4;
        int b0 = c * 8192 + ((row * 64 + scol * 2) ^ sw);
        int b1 = c * 8192 + ((row * 64 + scol * 2 + 16) ^ sw);
        *(uint4*)(w2img + b0) = h0;
        *(uint4*)(w2img + b1) = h1;
    }
}

// ---------------------------------------------------------------- score + ctx partial
// 4 waves x 32 rows = 128 rows/block, 512 blocks, 2 blocks/CU.
// Counted-vmcnt pipeline: 3 LDS slots (A fp32 16 KB + B f16 8 KB each),
// stage-ahead-1 via global_load_lds ONLY, asm s_waitcnt vmcnt(6) + asm
// s_barrier (both "memory"-fenced). Tile t+1's 6 loads stay in flight
// ACROSS the barrier -> HBM never drains to idle. Slot-reuse distance 3
// with one barrier/iter is race-free (writes into slot s at iter t touch
// data last read at iter t-2, sealed by barrier t-1).
__global__ __launch_bounds__(256, 2) void score_ctx_kernel(
        const float* __restrict__ keys, const char* __restrict__ w2img,
        const float* __restrict__ qp, const float* __restrict__ V,
        float* __restrict__ score_out, float* __restrict__ part_m,
        float* __restrict__ part_l, float* __restrict__ part_c) {
    __shared__ __align__(16) char slab[3][24576];   // [slot][A 16K | B 8K]
    __shared__ float sc[ROWS];
    __shared__ float pb[ROWS];
    __shared__ float red[8];

    const int blk  = blockIdx.x;          // 0..511
    const int m0   = blk * ROWS;
    const int b    = blk >> 4;            // 16 chunks per batch
    const int tid  = threadIdx.x;
    const int wave = tid >> 6;
    const int lane = tid & 63;
    const int l15  = lane & 15;
    const int l4   = lane >> 4;

    // A staging source (per-lane, inverse-swizzled granule):
    // instruction i of tile t: row = m0 + wave*32 + i*8 + (lane>>3),
    // granule byte = ((lane&7)*16) ^ ((lane>>3)<<4), + t*128
    const char* asrc0 = (const char*)keys
        + (size_t)(m0 + wave * 32 + (lane >> 3)) * (KD * 4)
        + (((lane & 7) * 16) ^ ((lane >> 3) << 4));

    // A read offsets: R = wave*32 + mi*16 + l15, byte R*128 + (l4*32 ^ swz)
    const int swz = (l15 & 7) << 4;
    const int ar0 = (wave * 32 + l15) * 128;
    const int ac0 = (l4 * 32) ^ swz;
    const int ac1 = (l4 * 32 + 16) ^ swz;
    // B frag byte offset within the 8 KB image region
    const int boff0 = 16384 + ((l15 * 64 + l4 * 16) ^ swz);

    f32x4 acc[2][8];
    #pragma unroll
    for (int mi = 0; mi < 2; ++mi)
        #pragma unroll
        for (int hj = 0; hj < 8; ++hj)
            acc[mi][hj] = (f32x4)0.f;

#define STAGE(slot, t) { \
        char* as_ = slab[slot]; \
        gload_lds16(asrc0 + 0 * 16384 + (t) * 128, as_ + wave * 4096 + 0 * 1024); \
        gload_lds16(asrc0 + 1 * 16384 + (t) * 128, as_ + wave * 4096 + 1 * 1024); \
        gload_lds16(asrc0 + 2 * 16384 + (t) * 128, as_ + wave * 4096 + 2 * 1024); \
        gload_lds16(asrc0 + 3 * 16384 + (t) * 128, as_ + wave * 4096 + 3 * 1024); \
        const char* g_ = w2img + (t) * 8192 + wave * 2048 + lane * 16; \
        gload_lds16(g_,        as_ + 16384 + wave * 2048); \
        gload_lds16(g_ + 1024, as_ + 16384 + wave * 2048 + 1024); }

    // prologue: stage tile 0 into slot 0
    STAGE(0, 0)

    #pragma unroll
    for (int t = 0; t < NT; ++t) {
        const int cs = t % 3;
        if (t + 1 < NT) STAGE((t + 1) % 3, t + 1)

        // drain tile t's 6 loads; leave tile t+1's 6 in flight
        if (t + 1 < NT) asm volatile("s_waitcnt vmcnt(6)" ::: "memory");
        else            asm volatile("s_waitcnt vmcnt(0)" ::: "memory");
        asm volatile("s_barrier" ::: "memory");

        const char* as = slab[cs];
        #pragma unroll
        for (int mi = 0; mi < 2; ++mi) {
            f32x4 lo = *(const f32x4*)(as + ar0 + mi * 2048 + ac0);
            f32x4 hi = *(const f32x4*)(as + ar0 + mi * 2048 + ac1);
            f16x8 af = cvtA4(lo, hi);
            __builtin_amdgcn_s_setprio(1);
            #pragma unroll
            for (int hj = 0; hj < 8; ++hj) {
                f16x8 bh = *(const f16x8*)(as + boff0 + hj * 1024);
                acc[mi][hj] = __builtin_amdgcn_mfma_f32_16x16x32_f16(af, bh, acc[mi][hj], 0, 0, 0);
            }
            __builtin_amdgcn_s_setprio(0);
        }
    }
#undef STAGE

    // epilogue operands
    float qv[8], vv[8];
    #pragma unroll
    for (int hj = 0; hj < 8; ++hj) {
        qv[hj] = qp[b * HD + hj * 16 + l15];
        vv[hj] = V[hj * 16 + l15];
    }

    // scores; C/D: col(h)=l15, row(m)=l4*4+j
    #pragma unroll
    for (int mi = 0; mi < 2; ++mi) {
        #pragma unroll
        for (int j = 0; j < 4; ++j) {
            float p = 0.f;
            #pragma unroll
            for (int hj = 0; hj < 8; ++hj) {
                float x = qv[hj] + acc[mi][hj][j];
                float e = __expf(2.f * x);
                float th = 1.f - 2.f * __builtin_amdgcn_rcpf(1.f + e);
                p += th * vv[hj];
            }
            #pragma unroll
            for (int off = 1; off < 16; off <<= 1) p += __shfl_xor(p, off);
            if (l15 == 0) {
                int r = wave * 32 + mi * 16 + l4 * 4 + j;
                score_out[m0 + r] = p;
                sc[r] = p;
            }
        }
    }
    __syncthreads();

    // block softmax partials over 128 rows
    float s_val = sc[tid & 127];
    float mx = s_val;
    #pragma unroll
    for (int off = 32; off >= 1; off >>= 1) mx = fmaxf(mx, __shfl_xor(mx, off));
    if (lane == 0) red[wave] = mx;
    __syncthreads();
    float m = fmaxf(fmaxf(red[0], red[1]), fmaxf(red[2], red[3]));
    float p = __expf(s_val - m);
    if (tid < 128) pb[tid] = p;
    float ps = p;
    #pragma unroll
    for (int off = 32; off >= 1; off >>= 1) ps += __shfl_xor(ps, off);
    if (lane == 0) red[4 + wave] = ps;
    __syncthreads();
    if (tid == 0) {
        part_m[blk] = m;
        part_l[blk] = red[4] + red[5];   // waves 0,1 cover rows 0..127
    }

    // context partial GEMV: c[col] = sum_s pb[s] * keys[m0+s, col]  (L2-hot)
    int col = tid * 2;
    float c0 = 0.f, c1 = 0.f;
    const float* kb2 = keys + (size_t)m0 * KD + col;
    #pragma unroll 4
    for (int s = 0; s < ROWS; ++s) {
        float w = pb[s];
        float2 kv = *(const float2*)(kb2 + (size_t)s * KD);
        c0 = fmaf(w, kv.x, c0);
        c1 = fmaf(w, kv.y, c1);
    }
    *(float2*)(part_c + (size_t)blk * KD + col) = make_float2(c0, c1);
}

// ---------------------------------------------------------------- finalize
__global__ __launch_bounds__(256) void finalize_kernel(
        const float* __restrict__ part_m, const float* __restrict__ part_l,
        const float* __restrict__ part_c, float* __restrict__ ctx,
        float* __restrict__ wts) {
    int b = blockIdx.x;
    int tid = threadIdx.x;
    float M = -1e30f;
    #pragma unroll
    for (int i = 0; i < NCHUNK; ++i) M = fmaxf(M, part_m[b * NCHUNK + i]);
    float e[NCHUNK];
    float L = 0.f;
    #pragma unroll
    for (int i = 0; i < NCHUNK; ++i) {
        e[i] = __expf(part_m[b * NCHUNK + i] - M);
        L += e[i] * part_l[b * NCHUNK + i];
    }
    float invL = 1.f / L;
    #pragma unroll
    for (int r = 0; r < 8; ++r) {
        int s = tid + r * 256;
        float scv = wts[b * SEQ + s];
        wts[b * SEQ + s] = __expf(scv - M) * invL;
    }
    #pragma unroll
    for (int g = 0; g < 2; ++g) {
        int col = tid + g * 256;
        float acc = 0.f;
        #pragma unroll
        for (int i = 0; i < NCHUNK; ++i)
            acc += e[i] * part_c[(size_t)(b * NCHUNK + i) * KD + col];
        ctx[b * KD + col] = acc * invL;
    }
}

// ---------------------------------------------------------------- launch
extern "C" void kernel_launch(void* const* d_in, const int* in_sizes, int n_in,
                              void* d_out, int out_size, void* d_ws, size_t ws_size,
                              hipStream_t stream) {
    const float* query = (const float*)d_in[0];
    const float* keys  = (const float*)d_in[1];
    const float* W1    = (const float*)d_in[2];
    const float* W2    = (const float*)d_in[3];
    const float* V     = (const float*)d_in[4];

    float* ctx = (float*)d_out;
    float* wts = (float*)d_out + BATCH * KD;

    char* wsb     = (char*)d_ws;
    float* qp     = (float*)wsb;                       // 16 KB
    char*  w2img  = wsb + 16 * 1024;                   // 128 KB
    float* part_m = (float*)(wsb + 144 * 1024);        // 2 KB
    float* part_l = (float*)(wsb + 146 * 1024);        // 2 KB
    float* part_c = (float*)(wsb + 148 * 1024);        // 1 MB

    prep_kernel<<<528, 256, 0, stream>>>(query, W1, W2, qp, w2img);
    score_ctx_kernel<<<BATCH * NCHUNK, 256, 0, stream>>>(
        keys, w2img, qp, V, wts, part_m, part_l, part_c);
    finalize_kernel<<<BATCH, 256, 0, stream>>>(part_m, part_l, part_c, ctx, wts);
}